// Round 6
// baseline (152.790 us; speedup 1.0000x reference)
//
#include <hip/hip_runtime.h>
#include <hip/hip_fp16.h>

// CTC greedy decode + CTC loss, fused. B=1024, T=256, V=64, blank=63.
// 1024 blocks x 64 threads (ONE wave per batch row, no barriers).
// Phase A: coalesced loads, packed-key argmax butterfly, fp16 probs stored
//          transposed [v2][t] with XOR bank swizzle.
// Phase B: label merge/scan (r4-verified code path).
// Phase C: prob-domain forward DP, no renorm (underflow == reference 0),
//          ds_read_b128 gathers (4 steps per load), DPP wave_shr neighbor.
// out: [0,B*T) labels | [B*T,+B) lengths | [B*T+B,+B) probability

#define BB 1024
#define TT 256
#define VV 64
#define BLANKC 63
#define K_LOG2E 1.44269504088896340736f

typedef __fp16 half2v __attribute__((ext_vector_type(2)));

__device__ __forceinline__ float wave_shr1(float v) {
    // v_mov_b32_dpp wave_shr:1 — lane l gets lane l-1's value; lane 0 -> 0
    return __int_as_float(__builtin_amdgcn_update_dpp(
        0, __float_as_int(v), 0x138, 0xf, 0xf, false));
}

// monotone key packing (value, first-index) for argmax-by-unsigned-max
__device__ __forceinline__ unsigned key_of(float x, int v) {
    unsigned u = __float_as_uint(x);
    unsigned k = u ^ (unsigned)(((int)u >> 31) | 0x80000000);
    return (k & ~63u) | (unsigned)(63 - v);
}

__device__ __forceinline__ float h2f_sel(unsigned w, unsigned sh) {
    return __half2float(__ushort_as_half((unsigned short)(w >> sh)));
}

// one DP step (state s=8*lane+j in a_j; a8 = state 512 on lane 63)
#define STEP(Q0, Q1, Q2, Q3, PBV) { \
    const float nb  = wave_shr1(a7); \
    const float na0 = (a0 + nb) * (PBV); \
    const float na1 = fmaf(sk0, nb, a1 + a0) * (Q0); \
    const float na2 = (a2 + a1) * (PBV); \
    const float na3 = fmaf(sk1, a1, a3 + a2) * (Q1); \
    const float na4 = (a4 + a3) * (PBV); \
    const float na5 = fmaf(sk2, a3, a5 + a4) * (Q2); \
    const float na6 = (a6 + a5) * (PBV); \
    const float na7 = fmaf(sk3, a5, a7 + a6) * (Q3); \
    a8 = (a8 + a7) * (PBV); \
    a0 = na0; a1 = na1; a2 = na2; a3 = na3; \
    a4 = na4; a5 = na5; a6 = na6; a7 = na7; }

#define STEPW(W0, W1, W2, W3, WB) { \
    const float q0  = h2f_sel(W0, sh0); \
    const float q1  = h2f_sel(W1, sh1); \
    const float q2  = h2f_sel(W2, sh2); \
    const float q3  = h2f_sel(W3, sh3); \
    const float pbv = __half2float(__ushort_as_half((unsigned short)((WB) >> 16))); \
    STEP(q0, q1, q2, q3, pbv) }

#define STEP4(G0, G1, G2, G3, GB) \
    STEPW(G0.x, G1.x, G2.x, G3.x, GB.x) \
    STEPW(G0.y, G1.y, G2.y, G3.y, GB.y) \
    STEPW(G0.z, G1.z, G2.z, G3.z, GB.z) \
    STEPW(G0.w, G1.w, G2.w, G3.w, GB.w)

// load one 4-step batch: 4 label columns + blank column (b128 each)
#define GLOAD(P, T0) { \
    P##b = *(const uint4*)(P2s + (7936 + (((T0)) ^ 28))); \
    P##0 = *(const uint4*)(P2s + c_o0 + (((T0)) ^ c_k0)); \
    P##1 = *(const uint4*)(P2s + c_o1 + (((T0)) ^ c_k1)); \
    P##2 = *(const uint4*)(P2s + c_o2 + (((T0)) ^ c_k2)); \
    P##3 = *(const uint4*)(P2s + c_o3 + (((T0)) ^ c_k3)); }

__global__ __launch_bounds__(64, 1) void ctc_fused(const float* __restrict__ logits,
                                                   float* __restrict__ out)
{
    // P2s[v2*256 + (t ^ ((v2&7)<<2))] = packed fp16 {vocab 2*v2 (lo), 2*v2+1 (hi)} at time t
    __shared__ unsigned P2s[32 * 256];                 // 32KB
    __shared__ int pred_s[TT];                         // 1KB
    __shared__ int lab_s[TT];                          // 1KB
    __shared__ __align__(16) float alpha_s[516];       // ~2KB

    const int lane = threadIdx.x;
    const int b    = blockIdx.x;
    const int q16  = lane & 15;                        // vocab quad (4q..4q+3)
    const int sub  = lane >> 4;                        // timestep within group

    const float4* Lg4 = (const float4*)(logits + (size_t)b * (TT * VV));

    // ---------------- Phase A: stats + fp16 transposed probs ----------------
    #pragma unroll 8
    for (int i = 0; i < 64; ++i) {                     // group = timesteps 4i..4i+3
        const float4 x = Lg4[i * 64 + lane];
        const int tg = 4 * i + sub;

        unsigned km = key_of(x.x, 4 * q16 + 0);
        km = max(km, key_of(x.y, 4 * q16 + 1));
        km = max(km, key_of(x.z, 4 * q16 + 2));
        km = max(km, key_of(x.w, 4 * q16 + 3));
        #pragma unroll
        for (int o = 1; o < 16; o <<= 1)
            km = max(km, (unsigned)__shfl_xor((int)km, o, 64));
        const int idx = 63 - (int)(km & 63u);
        // approximate max value (low 6 mantissa bits lost; cancels in p=e/S)
        const unsigned ku = km & ~63u;
        const unsigned mu = (ku & 0x80000000u) ? (ku & 0x7fffffffu) : ~ku;
        const float mA = __uint_as_float(mu);

        const float e0 = exp2f((x.x - mA) * K_LOG2E);
        const float e1 = exp2f((x.y - mA) * K_LOG2E);
        const float e2 = exp2f((x.z - mA) * K_LOG2E);
        const float e3 = exp2f((x.w - mA) * K_LOG2E);
        float S = (e0 + e1) + (e2 + e3);
        #pragma unroll
        for (int o = 1; o < 16; o <<= 1)
            S += __shfl_xor(S, o, 64);
        const float rS = __builtin_amdgcn_rcpf(S);

        const half2v hA = __builtin_amdgcn_cvt_pkrtz(e0 * rS, e1 * rS);
        const half2v hB = __builtin_amdgcn_cvt_pkrtz(e2 * rS, e3 * rS);
        const int v2a = 2 * q16, v2b = 2 * q16 + 1;
        P2s[v2a * 256 + (tg ^ ((v2a & 7) << 2))] = __builtin_bit_cast(unsigned, hA);
        P2s[v2b * 256 + (tg ^ ((v2b & 7) << 2))] = __builtin_bit_cast(unsigned, hB);
        if (q16 == 0) pred_s[tg] = idx;
    }

    // ---------------- Phase B: labels (merge repeats, drop blanks) ----------
    const int4 pc = ((const int4*)pred_s)[lane];
    const int p0 = pc.x, p1 = pc.y, p2 = pc.z, p3 = pc.w;
    int pl = __shfl_up(p3, 1, 64); if (lane == 0) pl = -1;
    const int k0 = (p0 != BLANKC && p0 != pl);
    const int k1 = (p1 != BLANKC && p1 != p0);
    const int k2 = (p2 != BLANKC && p2 != p1);
    const int k3 = (p3 != BLANKC && p3 != p2);
    const int cnt = k0 + k1 + k2 + k3;
    int sc = cnt;
    #pragma unroll
    for (int off = 1; off < 64; off <<= 1) {
        int t = __shfl_up(sc, off, 64);
        if (lane >= off) sc += t;
    }
    const int length = __shfl(sc, 63, 64);
    int pos = sc - cnt;
    ((int4*)lab_s)[lane] = make_int4(BLANKC, BLANKC, BLANKC, BLANKC);
    if (k0) lab_s[pos++] = p0;         // same-wave LDS ops are program-ordered
    if (k1) lab_s[pos++] = p1;
    if (k2) lab_s[pos++] = p2;
    if (k3) lab_s[pos++] = p3;

    const int4 lq = ((const int4*)lab_s)[lane];
    ((float4*)(out + (size_t)b * TT))[lane] =
        make_float4((float)lq.x, (float)lq.y, (float)lq.z, (float)lq.w);
    if (lane == 0) out[(size_t)BB * TT + b] = (float)length;

    int lprev = __shfl_up(lq.w, 1, 64); if (lane == 0) lprev = BLANKC;
    const float sk0 = (lq.x != BLANKC && lq.x != lprev) ? 1.0f : 0.0f;
    const float sk1 = (lq.y != BLANKC && lq.y != lq.x) ? 1.0f : 0.0f;
    const float sk2 = (lq.z != BLANKC && lq.z != lq.y) ? 1.0f : 0.0f;
    const float sk3 = (lq.w != BLANKC && lq.w != lq.z) ? 1.0f : 0.0f;

    // per-slot gather constants (element units into P2s)
    const int c_o0 = (lq.x >> 1) * 256, c_k0 = ((lq.x >> 1) & 7) << 2;
    const int c_o1 = (lq.y >> 1) * 256, c_k1 = ((lq.y >> 1) & 7) << 2;
    const int c_o2 = (lq.z >> 1) * 256, c_k2 = ((lq.z >> 1) & 7) << 2;
    const int c_o3 = (lq.w >> 1) * 256, c_k3 = ((lq.w >> 1) & 7) << 2;
    const unsigned sh0 = (lq.x & 1) * 16, sh1 = (lq.y & 1) * 16;
    const unsigned sh2 = (lq.z & 1) * 16, sh3 = (lq.w & 1) * 16;

    // ---------------- Phase C: forward DP, no renorm ------------------------
    float a0=0.f,a1=0.f,a2=0.f,a3=0.f,a4=0.f,a5=0.f,a6=0.f,a7=0.f,a8=0.f;
    if (lane == 0) a0 = 1.0f;

    uint4 A0, A1, A2, A3, Ab, B0, B1, B2, B3, Bb;
    GLOAD(A, 0);
    #pragma unroll 1
    for (int cc = 0; cc < 32; ++cc) {                  // 8 steps per iteration
        const int t0 = cc * 8;
        GLOAD(B, t0 + 4);
        STEP4(A0, A1, A2, A3, Ab);                     // steps t0..t0+3
        if (cc < 31) GLOAD(A, t0 + 8);
        STEP4(B0, B1, B2, B3, Bb);                     // steps t0+4..t0+7
    }

    // ---------------- epilogue: probability = alpha[end] + alpha[end-1] -----
    ((float4*)alpha_s)[2 * lane]     = make_float4(a0, a1, a2, a3);
    ((float4*)alpha_s)[2 * lane + 1] = make_float4(a4, a5, a6, a7);
    if (lane == 63) alpha_s[512] = a8;
    if (lane == 0) {
        const int end = 2 * length;
        const float e1 = alpha_s[end];
        const float e2 = (length > 0) ? alpha_s[end - 1] : 0.0f;
        out[(size_t)BB * TT + BB + b] = e1 + e2;
    }
}

extern "C" void kernel_launch(void* const* d_in, const int* in_sizes, int n_in,
                              void* d_out, int out_size, void* d_ws, size_t ws_size,
                              hipStream_t stream)
{
    const float* logits = (const float*)d_in[0];
    float* out = (float*)d_out;
    hipLaunchKernelGGL(ctc_fused, dim3(BB), dim3(64), 0, stream, logits, out);
}

// Round 7
// 111.633 us; speedup vs baseline: 1.3687x; 1.3687x over previous
//
#include <hip/hip_runtime.h>
#include <hip/hip_fp16.h>

// CTC greedy decode + CTC loss, fused. B=1024, T=256, V=64, blank=63.
// 1024 blocks x 64 threads (ONE wave per batch row, no barriers, grid-limited
// to 4 blocks/CU = 1 wave/SIMD -> all latency must be hidden by ILP).
// Phase A: 4-deep software-prefetched float4 loads; per-timestep (16-lane DPP
//          row) argmax + sum via row_ror rotation-allreduce (no LDS shuffles);
//          fp16 probs stored transposed [v2][t] with XOR bank swizzle.
// Phase B: label merge/scan (r4/r6-verified).
// Phase C: prob-domain forward DP, no renorm (underflow == reference 0),
//          ds_read_b128 gathers (4 steps per load), DPP wave_shr neighbor.
// out: [0,B*T) labels | [B*T,+B) lengths | [B*T+B,+B) probability

#define BB 1024
#define TT 256
#define VV 64
#define BLANKC 63
#define K_LOG2E 1.44269504088896340736f

typedef __fp16 half2v __attribute__((ext_vector_type(2)));

__device__ __forceinline__ float wave_shr1(float v) {
    // v_mov_b32_dpp wave_shr:1 — lane l gets lane l-1's value; lane 0 -> 0
    return __int_as_float(__builtin_amdgcn_update_dpp(
        0, __float_as_int(v), 0x138, 0xf, 0xf, false));
}

// DPP row_ror:N rotation within the 16-lane row (N = 1,2,4,8 -> ctrl 0x120+N)
template <int C>
__device__ __forceinline__ unsigned dpp_rot_maxu(unsigned v) {
    unsigned r = (unsigned)__builtin_amdgcn_update_dpp(
        0, (int)v, C, 0xf, 0xf, false);
    return v > r ? v : r;
}
template <int C>
__device__ __forceinline__ float dpp_rot_addf(float v) {
    float r = __int_as_float(__builtin_amdgcn_update_dpp(
        0, __float_as_int(v), C, 0xf, 0xf, false));
    return v + r;
}

// monotone key packing (value, first-index) for argmax-by-unsigned-max
__device__ __forceinline__ unsigned key_of(float x, int v) {
    unsigned u = __float_as_uint(x);
    unsigned k = u ^ (unsigned)(((int)u >> 31) | 0x80000000);
    return (k & ~63u) | (unsigned)(63 - v);
}

__device__ __forceinline__ float h2f_sel(unsigned w, unsigned sh) {
    return __half2float(__ushort_as_half((unsigned short)(w >> sh)));
}

// process one row-group: float4 X = logits quad for timestep tg=4*(I)+sub
#define PROC(X, I) { \
    const int tg = 4 * (I) + sub; \
    unsigned km = key_of((X).x, 4 * q16 + 0); \
    km = max(km, key_of((X).y, 4 * q16 + 1)); \
    km = max(km, key_of((X).z, 4 * q16 + 2)); \
    km = max(km, key_of((X).w, 4 * q16 + 3)); \
    km = dpp_rot_maxu<0x121>(km); \
    km = dpp_rot_maxu<0x122>(km); \
    km = dpp_rot_maxu<0x124>(km); \
    km = dpp_rot_maxu<0x128>(km); \
    const unsigned ku = km & ~63u; \
    const unsigned mu = (ku & 0x80000000u) ? (ku & 0x7fffffffu) : ~ku; \
    const float mA = __uint_as_float(mu); \
    const float e0 = exp2f(((X).x - mA) * K_LOG2E); \
    const float e1 = exp2f(((X).y - mA) * K_LOG2E); \
    const float e2 = exp2f(((X).z - mA) * K_LOG2E); \
    const float e3 = exp2f(((X).w - mA) * K_LOG2E); \
    float S = (e0 + e1) + (e2 + e3); \
    S = dpp_rot_addf<0x121>(S); \
    S = dpp_rot_addf<0x122>(S); \
    S = dpp_rot_addf<0x124>(S); \
    S = dpp_rot_addf<0x128>(S); \
    const float rS = __builtin_amdgcn_rcpf(S); \
    const half2v hA = __builtin_amdgcn_cvt_pkrtz(e0 * rS, e1 * rS); \
    const half2v hB = __builtin_amdgcn_cvt_pkrtz(e2 * rS, e3 * rS); \
    P2s[v2a * 256 + (tg ^ ka)] = __builtin_bit_cast(unsigned, hA); \
    P2s[v2b * 256 + (tg ^ kb)] = __builtin_bit_cast(unsigned, hB); \
    if (q16 == 0) pred_s[tg] = 63 - (int)(km & 63u); \
}

// one DP step (state s=8*lane+j in a_j; a8 = state 512 on lane 63)
#define STEP(Q0, Q1, Q2, Q3, PBV) { \
    const float nb  = wave_shr1(a7); \
    const float na0 = (a0 + nb) * (PBV); \
    const float na1 = fmaf(sk0, nb, a1 + a0) * (Q0); \
    const float na2 = (a2 + a1) * (PBV); \
    const float na3 = fmaf(sk1, a1, a3 + a2) * (Q1); \
    const float na4 = (a4 + a3) * (PBV); \
    const float na5 = fmaf(sk2, a3, a5 + a4) * (Q2); \
    const float na6 = (a6 + a5) * (PBV); \
    const float na7 = fmaf(sk3, a5, a7 + a6) * (Q3); \
    a8 = (a8 + a7) * (PBV); \
    a0 = na0; a1 = na1; a2 = na2; a3 = na3; \
    a4 = na4; a5 = na5; a6 = na6; a7 = na7; }

#define STEPW(W0, W1, W2, W3, WB) { \
    const float q0  = h2f_sel(W0, sh0); \
    const float q1  = h2f_sel(W1, sh1); \
    const float q2  = h2f_sel(W2, sh2); \
    const float q3  = h2f_sel(W3, sh3); \
    const float pbv = __half2float(__ushort_as_half((unsigned short)((WB) >> 16))); \
    STEP(q0, q1, q2, q3, pbv) }

#define STEP4(G0, G1, G2, G3, GB) \
    STEPW(G0.x, G1.x, G2.x, G3.x, GB.x) \
    STEPW(G0.y, G1.y, G2.y, G3.y, GB.y) \
    STEPW(G0.z, G1.z, G2.z, G3.z, GB.z) \
    STEPW(G0.w, G1.w, G2.w, G3.w, GB.w)

// load one 4-step batch: 4 label columns + blank column (b128 each)
#define GLOAD(P, T0) { \
    P##b = *(const uint4*)(P2s + (7936 + (((T0)) ^ 28))); \
    P##0 = *(const uint4*)(P2s + c_o0 + (((T0)) ^ c_k0)); \
    P##1 = *(const uint4*)(P2s + c_o1 + (((T0)) ^ c_k1)); \
    P##2 = *(const uint4*)(P2s + c_o2 + (((T0)) ^ c_k2)); \
    P##3 = *(const uint4*)(P2s + c_o3 + (((T0)) ^ c_k3)); }

__global__ __launch_bounds__(64, 1) void ctc_fused(const float* __restrict__ logits,
                                                   float* __restrict__ out)
{
    // P2s[v2*256 + (t ^ ((v2&7)<<2))] = packed fp16 {vocab 2*v2, 2*v2+1} at t
    __shared__ unsigned P2s[32 * 256];                 // 32KB
    __shared__ int pred_s[TT];                         // 1KB
    __shared__ int lab_s[TT];                          // 1KB
    __shared__ __align__(16) float alpha_s[516];       // ~2KB

    const int lane = threadIdx.x;
    const int b    = blockIdx.x;
    const int q16  = lane & 15;                        // vocab quad (4q..4q+3)
    const int sub  = lane >> 4;                        // timestep within group
    const int v2a  = 2 * q16, v2b = 2 * q16 + 1;
    const int ka   = (v2a & 7) << 2, kb = (v2b & 7) << 2;

    const float4* Lg4 = (const float4*)(logits + (size_t)b * (TT * VV));

    // ---------------- Phase A: stats + fp16 transposed probs ----------------
    // 4-deep software prefetch: rows i+4..i+7 in flight while rows i..i+3 run
    float4 q0 = Lg4[0 * 64 + lane], q1 = Lg4[1 * 64 + lane];
    float4 q2 = Lg4[2 * 64 + lane], q3 = Lg4[3 * 64 + lane];
    #pragma unroll 2
    for (int i = 0; i < 64; i += 4) {
        const int ip = (i + 4 < 64) ? (i + 4) : 0;     // wrap (redundant, L2-hit)
        const float4 n0 = Lg4[(ip + 0) * 64 + lane];
        const float4 n1 = Lg4[(ip + 1) * 64 + lane];
        const float4 n2 = Lg4[(ip + 2) * 64 + lane];
        const float4 n3 = Lg4[(ip + 3) * 64 + lane];
        PROC(q0, i)
        PROC(q1, i + 1)
        PROC(q2, i + 2)
        PROC(q3, i + 3)
        q0 = n0; q1 = n1; q2 = n2; q3 = n3;
    }

    // ---------------- Phase B: labels (merge repeats, drop blanks) ----------
    const int4 pc = ((const int4*)pred_s)[lane];
    const int p0 = pc.x, p1 = pc.y, p2 = pc.z, p3 = pc.w;
    int pl = __shfl_up(p3, 1, 64); if (lane == 0) pl = -1;
    const int k0 = (p0 != BLANKC && p0 != pl);
    const int k1 = (p1 != BLANKC && p1 != p0);
    const int k2 = (p2 != BLANKC && p2 != p1);
    const int k3 = (p3 != BLANKC && p3 != p2);
    const int cnt = k0 + k1 + k2 + k3;
    int sc = cnt;
    #pragma unroll
    for (int off = 1; off < 64; off <<= 1) {
        int t = __shfl_up(sc, off, 64);
        if (lane >= off) sc += t;
    }
    const int length = __shfl(sc, 63, 64);
    int pos = sc - cnt;
    ((int4*)lab_s)[lane] = make_int4(BLANKC, BLANKC, BLANKC, BLANKC);
    if (k0) lab_s[pos++] = p0;         // same-wave LDS ops are program-ordered
    if (k1) lab_s[pos++] = p1;
    if (k2) lab_s[pos++] = p2;
    if (k3) lab_s[pos++] = p3;

    const int4 lq = ((const int4*)lab_s)[lane];
    ((float4*)(out + (size_t)b * TT))[lane] =
        make_float4((float)lq.x, (float)lq.y, (float)lq.z, (float)lq.w);
    if (lane == 0) out[(size_t)BB * TT + b] = (float)length;

    int lprev = __shfl_up(lq.w, 1, 64); if (lane == 0) lprev = BLANKC;
    const float sk0 = (lq.x != BLANKC && lq.x != lprev) ? 1.0f : 0.0f;
    const float sk1 = (lq.y != BLANKC && lq.y != lq.x) ? 1.0f : 0.0f;
    const float sk2 = (lq.z != BLANKC && lq.z != lq.y) ? 1.0f : 0.0f;
    const float sk3 = (lq.w != BLANKC && lq.w != lq.z) ? 1.0f : 0.0f;

    // per-slot gather constants (element units into P2s)
    const int c_o0 = (lq.x >> 1) * 256, c_k0 = ((lq.x >> 1) & 7) << 2;
    const int c_o1 = (lq.y >> 1) * 256, c_k1 = ((lq.y >> 1) & 7) << 2;
    const int c_o2 = (lq.z >> 1) * 256, c_k2 = ((lq.z >> 1) & 7) << 2;
    const int c_o3 = (lq.w >> 1) * 256, c_k3 = ((lq.w >> 1) & 7) << 2;
    const unsigned sh0 = (lq.x & 1) * 16, sh1 = (lq.y & 1) * 16;
    const unsigned sh2 = (lq.z & 1) * 16, sh3 = (lq.w & 1) * 16;

    // ---------------- Phase C: forward DP, no renorm ------------------------
    float a0=0.f,a1=0.f,a2=0.f,a3=0.f,a4=0.f,a5=0.f,a6=0.f,a7=0.f,a8=0.f;
    if (lane == 0) a0 = 1.0f;

    uint4 A0, A1, A2, A3, Ab, B0, B1, B2, B3, Bb;
    GLOAD(A, 0);
    #pragma unroll 1
    for (int cc = 0; cc < 32; ++cc) {                  // 8 steps per iteration
        const int t0 = cc * 8;
        GLOAD(B, t0 + 4);
        STEP4(A0, A1, A2, A3, Ab);                     // steps t0..t0+3
        if (cc < 31) GLOAD(A, t0 + 8);
        STEP4(B0, B1, B2, B3, Bb);                     // steps t0+4..t0+7
    }

    // ---------------- epilogue: probability = alpha[end] + alpha[end-1] -----
    ((float4*)alpha_s)[2 * lane]     = make_float4(a0, a1, a2, a3);
    ((float4*)alpha_s)[2 * lane + 1] = make_float4(a4, a5, a6, a7);
    if (lane == 63) alpha_s[512] = a8;
    if (lane == 0) {
        const int end = 2 * length;
        const float e1 = alpha_s[end];
        const float e2 = (length > 0) ? alpha_s[end - 1] : 0.0f;
        out[(size_t)BB * TT + BB + b] = e1 + e2;
    }
}

extern "C" void kernel_launch(void* const* d_in, const int* in_sizes, int n_in,
                              void* d_out, int out_size, void* d_ws, size_t ws_size,
                              hipStream_t stream)
{
    const float* logits = (const float*)d_in[0];
    float* out = (float*)d_out;
    hipLaunchKernelGGL(ctc_fused, dim3(BB), dim3(64), 0, stream, logits, out);
}